// Round 8
// baseline (274.634 us; speedup 1.0000x reference)
//
#include <hip/hip_runtime.h>
#include <hip/hip_bf16.h>
#include <stdint.h>

#define Bsz 4096
#define Csz 1024

typedef __attribute__((ext_vector_type(8))) short short8;
typedef __attribute__((ext_vector_type(4))) float f32x4;

// order-preserving f32 -> u32 encoding (monotone for all non-NaN)
__device__ __forceinline__ unsigned fenc(float v) {
  unsigned u = __float_as_uint(v);
  return (u & 0x80000000u) ? ~u : (u | 0x80000000u);
}

__device__ __forceinline__ void load_lds16(const void* g, void* l) {
  __builtin_amdgcn_global_load_lds(
      (const __attribute__((address_space(1))) void*)g,
      (__attribute__((address_space(3))) void*)l, 16, 0, 0);
}

__device__ __forceinline__ uint32_t rotl32(uint32_t x, int r) {
  return (x << r) | (x >> (32 - r));
}

// ---------------- K1: row stats + bf16 cast + fused threefry rand_idx -------
__global__ __launch_bounds__(256) void k_rowstats(
    const float* __restrict__ outs, const int* __restrict__ label,
    unsigned short* __restrict__ xb, float* __restrict__ sq,
    float* __restrict__ ce, unsigned long long* __restrict__ hard,
    int* __restrict__ ridx, double* __restrict__ acc,
    unsigned int* __restrict__ cnt) {
  const int row = blockIdx.x;
  const int tid = threadIdx.x;
  const int lane = tid & 63, wid = tid >> 6;
  const float4 v = reinterpret_cast<const float4*>(outs + (size_t)row * Csz)[tid];

  if (row == 0 && tid == 0) { *acc = 0.0; *cnt = 0u; }  // reset fused-final state

  ushort4 u4;
  {
    __hip_bfloat16 h;
    h = __float2bfloat16(v.x); u4.x = *reinterpret_cast<const unsigned short*>(&h);
    h = __float2bfloat16(v.y); u4.y = *reinterpret_cast<const unsigned short*>(&h);
    h = __float2bfloat16(v.z); u4.z = *reinterpret_cast<const unsigned short*>(&h);
    h = __float2bfloat16(v.w); u4.w = *reinterpret_cast<const unsigned short*>(&h);
  }
  reinterpret_cast<ushort4*>(xb + (size_t)row * Csz)[tid] = u4;

  __shared__ float wred[3][4];
  float mx = fmaxf(fmaxf(v.x, v.y), fmaxf(v.z, v.w));
#pragma unroll
  for (int off = 32; off; off >>= 1) mx = fmaxf(mx, __shfl_xor(mx, off, 64));
  if (lane == 0) wred[0][wid] = mx;
  __syncthreads();
  mx = fmaxf(fmaxf(wred[0][0], wred[0][1]), fmaxf(wred[0][2], wred[0][3]));

  float se = expf(v.x - mx) + expf(v.y - mx) + expf(v.z - mx) + expf(v.w - mx);
  float s2 = v.x * v.x + v.y * v.y + v.z * v.z + v.w * v.w;
#pragma unroll
  for (int off = 32; off; off >>= 1) {
    se += __shfl_xor(se, off, 64);
    s2 += __shfl_xor(s2, off, 64);
  }
  if (lane == 0) { wred[1][wid] = se; wred[2][wid] = s2; }
  __syncthreads();
  if (tid == 0) {
    const float set = wred[1][0] + wred[1][1] + wred[1][2] + wred[1][3];
    const float sqt = wred[2][0] + wred[2][1] + wred[2][2] + wred[2][3];
    sq[row] = sqt;
    ce[row] = -(outs[(size_t)row * Csz + label[row]] - mx - logf(set));
    hard[row] = 0ull;  // fused memset
  }

  if (row >= 2048) return;

  // ---- fused rand_idx: rows row and row+2048 ----
  const int i = row;
  const int li0 = label[i], li1 = label[i + 2048];
  const uint32_t k1c = 42u, k2c = 0x1BD11BDAu ^ 42u;
  unsigned long long b0 = 0ull, b1 = 0ull;
  for (int j = tid; j < Bsz; j += 256) {
    uint32_t x0 = (uint32_t)(i * Bsz + j);
    uint32_t x1 = x0 + 8388608u;
    x1 += k1c;
#define RND(rt) { x0 += x1; x1 = rotl32(x1, rt); x1 ^= x0; }
    RND(13) RND(15) RND(26) RND(6)
    x0 += k1c; x1 += k2c + 1u;
    RND(17) RND(29) RND(16) RND(24)
    x0 += k2c; x1 += 2u;
    RND(13) RND(15) RND(26) RND(6)
    x1 += k1c + 3u;
    RND(17) RND(29) RND(16) RND(24)
    x0 += k1c; x1 += k2c + 4u;
    RND(13) RND(15) RND(26) RND(6)
    x0 += k2c; x1 += 5u;
#undef RND
    const int lj = label[j];
    if (lj != li0) {
      unsigned long long p = (((unsigned long long)(x0 >> 9)) << 32) | (uint32_t)(~j);
      if (p > b0) b0 = p;
    }
    if (lj != li1) {
      unsigned long long p = (((unsigned long long)(x1 >> 9)) << 32) | (uint32_t)(~j);
      if (p > b1) b1 = p;
    }
  }
#pragma unroll
  for (int off = 32; off; off >>= 1) {
    unsigned long long o0 = __shfl_xor(b0, off, 64); if (o0 > b0) b0 = o0;
    unsigned long long o1 = __shfl_xor(b1, off, 64); if (o1 > b1) b1 = o1;
  }
  __shared__ unsigned long long r0[4], r1[4];
  if (lane == 0) { r0[wid] = b0; r1[wid] = b1; }
  __syncthreads();
  if (tid == 0) {
#pragma unroll
    for (int w = 1; w < 4; ++w) {
      if (r0[w] > b0) b0 = r0[w];
      if (r1[w] > b1) b1 = r1[w];
    }
    ridx[i] = (int)(~(uint32_t)b0);
    ridx[i + 2048] = (int)(~(uint32_t)b1);
  }
}

// ---------------- K2: bf16 MFMA X·X^T, 256x256, fine-interleaved ------------
// 256 blocks (1/CU), 8 waves 2Mx4N, per-wave 128x64 = 8x4 frags of 16x16.
// BK=32, 32 K-tiles, FOUR LDS tile-buffers (128 KB), staging runs 2 tiles
// ahead. Per tile: 2 phases, each {ds_read subtile ∥ issue 1 half-stage ->
// barrier -> 16 MFMA (setprio) -> barrier}; vmcnt(4) ONLY at tile boundary
// (newest 4 insts = next tile's staging; everything older has landed).
// lgkmcnt(0) at boundary makes buffer WAR airtight (HW counter drain).
// Swizzle: stored chunk = logical chunk ^ (row&3) via pre-swizzled global
// source (gload_lds dest linear, rule #21); read xor fq^(fr&3); bank
// analysis: 16 rows over 4 xor-slots x 2 bank-halves -> free 2-way only.
__global__ __launch_bounds__(512, 2) void k_hard(
    const unsigned short* __restrict__ xb, const float* __restrict__ sq,
    const int* __restrict__ label, unsigned long long* __restrict__ hard) {
  __shared__ unsigned short As[4][256 * 32];
  __shared__ unsigned short Bs[4][256 * 32];

  const int bid = (int)blockIdx.x;
  const int swz = (bid & 7) * 32 + (bid >> 3);  // XCD swizzle (256 = 8*32)
  const int bi = swz >> 4, bj = swz & 15;

  const int tid = (int)threadIdx.x;
  const int wid = tid >> 6, lane = tid & 63;
  const int wm = wid >> 2;    // 0..1: wave row (128 rows)
  const int wn = wid & 3;     // 0..3: wave col (64 cols)
  const int fr = lane & 15;   // fragment row/col index
  const int fq = lane >> 4;   // k-quad index (chunk 0..3 of BK=32)
  const int rsx = fr & 3;     // read-side swizzle xor

  f32x4 acc[8][4];
#pragma unroll
  for (int m = 0; m < 8; ++m)
#pragma unroll
    for (int n = 0; n < 4; ++n) acc[m][n] = (f32x4){0.f, 0.f, 0.f, 0.f};

  const unsigned short* Ag = xb + (size_t)(bi * 256) * Csz;
  const unsigned short* Bg = xb + (size_t)(bj * 256) * Csz;
  const int lrow = lane >> 2;                       // 16 rows per staging inst
  const int lch = ((lane & 3) ^ (lrow & 3)) * 8;    // pre-swizzled source chunk

  auto STAGE_A = [&](int t) {  // 2 insts/wave
    const int kt = t * 32;
    unsigned short* dst = &As[t & 3][0];
#pragma unroll
    for (int c = 0; c < 2; ++c) {
      const int r = wid * 32 + c * 16;
      load_lds16(Ag + (size_t)(r + lrow) * Csz + kt + lch, dst + r * 32);
    }
  };
  auto STAGE_B = [&](int t) {  // 2 insts/wave
    const int kt = t * 32;
    unsigned short* dst = &Bs[t & 3][0];
#pragma unroll
    for (int c = 0; c < 2; ++c) {
      const int r = wid * 32 + c * 16;
      load_lds16(Bg + (size_t)(r + lrow) * Csz + kt + lch, dst + r * 32);
    }
  };

  short8 a[4], b[4];
  auto READ_B = [&](int t) {
#pragma unroll
    for (int n = 0; n < 4; ++n)
      b[n] = *reinterpret_cast<const short8*>(
          &Bs[t & 3][(wn * 64 + n * 16 + fr) * 32 + ((fq ^ rsx) * 8)]);
  };
  auto READ_A4 = [&](int t, int m0) {
#pragma unroll
    for (int m = 0; m < 4; ++m)
      a[m] = *reinterpret_cast<const short8*>(
          &As[t & 3][(wm * 128 + (m0 + m) * 16 + fr) * 32 + ((fq ^ rsx) * 8)]);
  };
  auto MFMA16 = [&](int m0) {
    __builtin_amdgcn_s_setprio(1);
#pragma unroll
    for (int m = 0; m < 4; ++m)
#pragma unroll
      for (int n = 0; n < 4; ++n)
        acc[m0 + m][n] =
            __builtin_amdgcn_mfma_f32_16x16x32_bf16(a[m], b[n], acc[m0 + m][n], 0, 0, 0);
    __builtin_amdgcn_s_setprio(0);
  };

  // prologue: tiles 0 and 1 fully staged (8 insts/wave in flight)
  STAGE_A(0); STAGE_B(0); STAGE_A(1); STAGE_B(1);

#pragma unroll 1
  for (int t = 0; t < 32; ++t) {
    // boundary: tile t landed (newest 4 insts = tile t+1); all LDS reads drained (WAR)
    if (t < 31) asm volatile("s_waitcnt vmcnt(4) lgkmcnt(0)" ::: "memory");
    else        asm volatile("s_waitcnt vmcnt(0) lgkmcnt(0)" ::: "memory");
    __builtin_amdgcn_sched_barrier(0);
    __builtin_amdgcn_s_barrier();
    // phase A: B-frags + A-rows 0-3, stage A(t+2)
    READ_B(t);
    READ_A4(t, 0);
    if (t < 30) STAGE_A(t + 2);
    __builtin_amdgcn_s_barrier();
    MFMA16(0);
    __builtin_amdgcn_s_barrier();
    // phase B: A-rows 4-7, stage B(t+2)
    READ_A4(t, 4);
    if (t < 30) STAGE_B(t + 2);
    __builtin_amdgcn_s_barrier();
    MFMA16(4);
  }

  const float cst = -2.0f * 1024.0f * 3.1622776601683794e-8f;  // -2*c*sqrt(1e-15)

  // epilogue: C/D layout col(B-side)=lane&15, row(A-side)=fq*4+reg
#pragma unroll
  for (int m = 0; m < 8; ++m) {
#pragma unroll
    for (int r = 0; r < 4; ++r) {
      const int i = bi * 256 + wm * 128 + m * 16 + fq * 4 + r;
      const int li = label[i];
      const float sqi = sq[i];
      float bestv = -3.0e38f;
      int bestj = 0x7FFFFFFF;
#pragma unroll
      for (int n = 0; n < 4; ++n) {
        const int j = bj * 256 + wn * 64 + n * 16 + fr;
        const float val = sqi + sq[j] - 2.0f * acc[m][n][r] + cst;
        if (label[j] != li && val > bestv) { bestv = val; bestj = j; }
      }
      unsigned long long pack =
          (bestj == 0x7FFFFFFF)
              ? 0ull
              : (((unsigned long long)fenc(bestv)) << 32) | (unsigned)(~bestj);
#pragma unroll
      for (int off = 1; off < 16; off <<= 1) {
        unsigned long long o = __shfl_xor(pack, off, 64);
        if (o > pack) pack = o;
      }
      if (fr == 0 && pack) atomicMax(&hard[i], pack);
    }
  }
}

// ---------------- K3: InfoNCE per-row + fused final reduction ----------------
// Each block: 3 f32 dots + 3-way log-softmax -> partial = ce[i] + 0.1*nce_i,
// atomicAdd(f64) into acc; last-finished block writes out[0].
__global__ __launch_bounds__(256) void k_ncefin(
    const float* __restrict__ outs, const float* __restrict__ centers,
    const int* __restrict__ label, const unsigned long long* __restrict__ hard,
    const int* __restrict__ ridx, const float* __restrict__ ce,
    double* __restrict__ acc, unsigned int* __restrict__ cnt,
    float* __restrict__ out) {
  const int i = blockIdx.x;
  const int tid = threadIdx.x;
  const int lane = tid & 63, wid = tid >> 6;
  const int li = label[i];
  const int jh = (int)(~(uint32_t)hard[i]);
  const int jr = ridx[i];
  const float4 aa = reinterpret_cast<const float4*>(outs + (size_t)i * Csz)[tid];
  const float4 cc = reinterpret_cast<const float4*>(centers + (size_t)li * Csz)[tid];
  const float4 rr = reinterpret_cast<const float4*>(outs + (size_t)jr * Csz)[tid];
  const float4 hh = reinterpret_cast<const float4*>(outs + (size_t)jh * Csz)[tid];
  float dp = aa.x * cc.x + aa.y * cc.y + aa.z * cc.z + aa.w * cc.w;
  float dr = aa.x * rr.x + aa.y * rr.y + aa.z * rr.z + aa.w * rr.w;
  float dh = aa.x * hh.x + aa.y * hh.y + aa.z * hh.z + aa.w * hh.w;
#pragma unroll
  for (int off = 32; off; off >>= 1) {
    dp += __shfl_xor(dp, off, 64);
    dr += __shfl_xor(dr, off, 64);
    dh += __shfl_xor(dh, off, 64);
  }
  __shared__ float w0[4], w1[4], w2[4];
  if (lane == 0) { w0[wid] = dp; w1[wid] = dr; w2[wid] = dh; }
  __syncthreads();
  if (tid == 0) {
    const float l0 = w0[0] + w0[1] + w0[2] + w0[3];
    const float l1 = w1[0] + w1[1] + w1[2] + w1[3];
    const float l2 = w2[0] + w2[1] + w2[2] + w2[3];
    const float m = fmaxf(l0, fmaxf(l1, l2));
    const float lse = logf(expf(l0 - m) + expf(l1 - m) + expf(l2 - m));
    const float nce_i = -(l0 - m - lse);
    atomicAdd(acc, (double)ce[i] + 0.1 * (double)nce_i);
    __threadfence();
    if (atomicAdd(cnt, 1u) == (unsigned)(Bsz - 1)) {
      const double s = atomicAdd(acc, 0.0);  // RMW read: final total
      out[0] = (float)(s / (double)Bsz);
    }
  }
}

extern "C" void kernel_launch(void* const* d_in, const int* in_sizes, int n_in,
                              void* d_out, int out_size, void* d_ws, size_t ws_size,
                              hipStream_t stream) {
  const float* outs = (const float*)d_in[0];
  const float* centers = (const float*)d_in[1];
  const int* label = (const int*)d_in[2];
  float* out = (float*)d_out;

  char* ws = (char*)d_ws;
  unsigned short* xb = (unsigned short*)ws;                            // 8 MB bf16 X
  unsigned long long* hard = (unsigned long long*)(ws + (8u << 20));   // 32 KB
  float* sq = (float*)(ws + (8u << 20) + 32768);                       // 16 KB
  float* ce = sq + Bsz;                                                // 16 KB
  int* ridx = (int*)(ce + Bsz);                                        // 16 KB
  double* acc = (double*)(ridx + Bsz);                                 // 8 B
  unsigned int* cnt = (unsigned int*)(acc + 1);                        // 4 B

  k_rowstats<<<Bsz, 256, 0, stream>>>(outs, label, xb, sq, ce, hard, ridx, acc, cnt);
  k_hard<<<256, 512, 0, stream>>>(xb, sq, label, hard);
  k_ncefin<<<Bsz, 256, 0, stream>>>(outs, centers, label, hard, ridx, ce, acc, cnt, out);
}

// Round 9
// 159.995 us; speedup vs baseline: 1.7165x; 1.7165x over previous
//
#include <hip/hip_runtime.h>
#include <hip/hip_bf16.h>
#include <stdint.h>

#define Bsz 4096
#define Csz 1024

typedef __attribute__((ext_vector_type(8))) short short8;
typedef __attribute__((ext_vector_type(4))) float f32x4;

// order-preserving f32 -> u32 encoding (monotone for all non-NaN)
__device__ __forceinline__ unsigned fenc(float v) {
  unsigned u = __float_as_uint(v);
  return (u & 0x80000000u) ? ~u : (u | 0x80000000u);
}

__device__ __forceinline__ void load_lds16(const void* g, void* l) {
  __builtin_amdgcn_global_load_lds(
      (const __attribute__((address_space(1))) void*)g,
      (__attribute__((address_space(3))) void*)l, 16, 0, 0);
}

__device__ __forceinline__ uint32_t rotl32(uint32_t x, int r) {
  return (x << r) | (x >> (32 - r));
}

// ---------------- K1: row stats + bf16 cast + fused threefry rand_idx -------
__global__ __launch_bounds__(256) void k_rowstats(
    const float* __restrict__ outs, const int* __restrict__ label,
    unsigned short* __restrict__ xb, float* __restrict__ sq,
    float* __restrict__ ce, unsigned long long* __restrict__ hard,
    int* __restrict__ ridx) {
  const int row = blockIdx.x;
  const int tid = threadIdx.x;
  const int lane = tid & 63, wid = tid >> 6;
  const float4 v = reinterpret_cast<const float4*>(outs + (size_t)row * Csz)[tid];

  ushort4 u4;
  {
    __hip_bfloat16 h;
    h = __float2bfloat16(v.x); u4.x = *reinterpret_cast<const unsigned short*>(&h);
    h = __float2bfloat16(v.y); u4.y = *reinterpret_cast<const unsigned short*>(&h);
    h = __float2bfloat16(v.z); u4.z = *reinterpret_cast<const unsigned short*>(&h);
    h = __float2bfloat16(v.w); u4.w = *reinterpret_cast<const unsigned short*>(&h);
  }
  reinterpret_cast<ushort4*>(xb + (size_t)row * Csz)[tid] = u4;

  __shared__ float wred[3][4];
  float mx = fmaxf(fmaxf(v.x, v.y), fmaxf(v.z, v.w));
#pragma unroll
  for (int off = 32; off; off >>= 1) mx = fmaxf(mx, __shfl_xor(mx, off, 64));
  if (lane == 0) wred[0][wid] = mx;
  __syncthreads();
  mx = fmaxf(fmaxf(wred[0][0], wred[0][1]), fmaxf(wred[0][2], wred[0][3]));

  float se = expf(v.x - mx) + expf(v.y - mx) + expf(v.z - mx) + expf(v.w - mx);
  float s2 = v.x * v.x + v.y * v.y + v.z * v.z + v.w * v.w;
#pragma unroll
  for (int off = 32; off; off >>= 1) {
    se += __shfl_xor(se, off, 64);
    s2 += __shfl_xor(s2, off, 64);
  }
  if (lane == 0) { wred[1][wid] = se; wred[2][wid] = s2; }
  __syncthreads();
  if (tid == 0) {
    const float set = wred[1][0] + wred[1][1] + wred[1][2] + wred[1][3];
    const float sqt = wred[2][0] + wred[2][1] + wred[2][2] + wred[2][3];
    sq[row] = sqt;
    ce[row] = -(outs[(size_t)row * Csz + label[row]] - mx - logf(set));
    hard[row] = 0ull;  // fused memset
  }

  if (row >= 2048) return;

  // ---- fused rand_idx: rows row and row+2048 ----
  const int i = row;
  const int li0 = label[i], li1 = label[i + 2048];
  const uint32_t k1c = 42u, k2c = 0x1BD11BDAu ^ 42u;
  unsigned long long b0 = 0ull, b1 = 0ull;
  for (int j = tid; j < Bsz; j += 256) {
    uint32_t x0 = (uint32_t)(i * Bsz + j);
    uint32_t x1 = x0 + 8388608u;
    x1 += k1c;
#define RND(rt) { x0 += x1; x1 = rotl32(x1, rt); x1 ^= x0; }
    RND(13) RND(15) RND(26) RND(6)
    x0 += k1c; x1 += k2c + 1u;
    RND(17) RND(29) RND(16) RND(24)
    x0 += k2c; x1 += 2u;
    RND(13) RND(15) RND(26) RND(6)
    x1 += k1c + 3u;
    RND(17) RND(29) RND(16) RND(24)
    x0 += k1c; x1 += k2c + 4u;
    RND(13) RND(15) RND(26) RND(6)
    x0 += k2c; x1 += 5u;
#undef RND
    const int lj = label[j];
    if (lj != li0) {
      unsigned long long p = (((unsigned long long)(x0 >> 9)) << 32) | (uint32_t)(~j);
      if (p > b0) b0 = p;
    }
    if (lj != li1) {
      unsigned long long p = (((unsigned long long)(x1 >> 9)) << 32) | (uint32_t)(~j);
      if (p > b1) b1 = p;
    }
  }
#pragma unroll
  for (int off = 32; off; off >>= 1) {
    unsigned long long o0 = __shfl_xor(b0, off, 64); if (o0 > b0) b0 = o0;
    unsigned long long o1 = __shfl_xor(b1, off, 64); if (o1 > b1) b1 = o1;
  }
  __shared__ unsigned long long r0[4], r1[4];
  if (lane == 0) { r0[wid] = b0; r1[wid] = b1; }
  __syncthreads();
  if (tid == 0) {
#pragma unroll
    for (int w = 1; w < 4; ++w) {
      if (r0[w] > b0) b0 = r0[w];
      if (r1[w] > b1) b1 = r1[w];
    }
    ridx[i] = (int)(~(uint32_t)b0);
    ridx[i + 2048] = (int)(~(uint32_t)b1);
  }
}

// ---------------- K2: bf16 MFMA X·X^T, 256x256, fine-interleaved ------------
// 256 blocks (1/CU), 8 waves 2Mx4N, per-wave 128x64 = 8x4 frags of 16x16.
// BK=32, 32 K-tiles, FOUR LDS tile-buffers (128 KB), staging runs 2 tiles
// ahead. Per tile: 2 phases, each {ds_read subtile ∥ issue 1 half-stage ->
// barrier -> 16 MFMA (setprio) -> barrier}; vmcnt(4) ONLY at tile boundary.
// lgkmcnt(0) at boundary makes buffer WAR airtight (HW counter drain).
// Swizzle: stored chunk = logical chunk ^ (row&3) via pre-swizzled global
// source (gload_lds dest linear, rule #21); read xor fq^(fr&3).
__global__ __launch_bounds__(512, 2) void k_hard(
    const unsigned short* __restrict__ xb, const float* __restrict__ sq,
    const int* __restrict__ label, unsigned long long* __restrict__ hard) {
  __shared__ unsigned short As[4][256 * 32];
  __shared__ unsigned short Bs[4][256 * 32];

  const int bid = (int)blockIdx.x;
  const int swz = (bid & 7) * 32 + (bid >> 3);  // XCD swizzle (256 = 8*32)
  const int bi = swz >> 4, bj = swz & 15;

  const int tid = (int)threadIdx.x;
  const int wid = tid >> 6, lane = tid & 63;
  const int wm = wid >> 2;    // 0..1: wave row (128 rows)
  const int wn = wid & 3;     // 0..3: wave col (64 cols)
  const int fr = lane & 15;   // fragment row/col index
  const int fq = lane >> 4;   // k-quad index (chunk 0..3 of BK=32)
  const int rsx = fr & 3;     // read-side swizzle xor

  f32x4 acc[8][4];
#pragma unroll
  for (int m = 0; m < 8; ++m)
#pragma unroll
    for (int n = 0; n < 4; ++n) acc[m][n] = (f32x4){0.f, 0.f, 0.f, 0.f};

  const unsigned short* Ag = xb + (size_t)(bi * 256) * Csz;
  const unsigned short* Bg = xb + (size_t)(bj * 256) * Csz;
  const int lrow = lane >> 2;                       // 16 rows per staging inst
  const int lch = ((lane & 3) ^ (lrow & 3)) * 8;    // pre-swizzled source chunk

  auto STAGE_A = [&](int t) {  // 2 insts/wave
    const int kt = t * 32;
    unsigned short* dst = &As[t & 3][0];
#pragma unroll
    for (int c = 0; c < 2; ++c) {
      const int r = wid * 32 + c * 16;
      load_lds16(Ag + (size_t)(r + lrow) * Csz + kt + lch, dst + r * 32);
    }
  };
  auto STAGE_B = [&](int t) {  // 2 insts/wave
    const int kt = t * 32;
    unsigned short* dst = &Bs[t & 3][0];
#pragma unroll
    for (int c = 0; c < 2; ++c) {
      const int r = wid * 32 + c * 16;
      load_lds16(Bg + (size_t)(r + lrow) * Csz + kt + lch, dst + r * 32);
    }
  };

  short8 a[4], b[4];
  auto READ_B = [&](int t) {
#pragma unroll
    for (int n = 0; n < 4; ++n)
      b[n] = *reinterpret_cast<const short8*>(
          &Bs[t & 3][(wn * 64 + n * 16 + fr) * 32 + ((fq ^ rsx) * 8)]);
  };
  auto READ_A4 = [&](int t, int m0) {
#pragma unroll
    for (int m = 0; m < 4; ++m)
      a[m] = *reinterpret_cast<const short8*>(
          &As[t & 3][(wm * 128 + (m0 + m) * 16 + fr) * 32 + ((fq ^ rsx) * 8)]);
  };
  auto MFMA16 = [&](int m0) {
    __builtin_amdgcn_s_setprio(1);
#pragma unroll
    for (int m = 0; m < 4; ++m)
#pragma unroll
      for (int n = 0; n < 4; ++n)
        acc[m0 + m][n] =
            __builtin_amdgcn_mfma_f32_16x16x32_bf16(a[m], b[n], acc[m0 + m][n], 0, 0, 0);
    __builtin_amdgcn_s_setprio(0);
  };

  // prologue: tiles 0 and 1 fully staged (8 insts/wave in flight)
  STAGE_A(0); STAGE_B(0); STAGE_A(1); STAGE_B(1);

#pragma unroll 1
  for (int t = 0; t < 32; ++t) {
    // boundary: tile t landed (newest 4 insts = tile t+1); LDS reads drained (WAR)
    if (t < 31) asm volatile("s_waitcnt vmcnt(4) lgkmcnt(0)" ::: "memory");
    else        asm volatile("s_waitcnt vmcnt(0) lgkmcnt(0)" ::: "memory");
    __builtin_amdgcn_sched_barrier(0);
    __builtin_amdgcn_s_barrier();
    // phase A: B-frags + A-rows 0-3, stage A(t+2)
    READ_B(t);
    READ_A4(t, 0);
    if (t < 30) STAGE_A(t + 2);
    __builtin_amdgcn_s_barrier();
    MFMA16(0);
    __builtin_amdgcn_s_barrier();
    // phase B: A-rows 4-7, stage B(t+2)
    READ_A4(t, 4);
    if (t < 30) STAGE_B(t + 2);
    __builtin_amdgcn_s_barrier();
    MFMA16(4);
  }

  const float cst = -2.0f * 1024.0f * 3.1622776601683794e-8f;  // -2*c*sqrt(1e-15)

  // epilogue: C/D layout col(B-side)=lane&15, row(A-side)=fq*4+reg
#pragma unroll
  for (int m = 0; m < 8; ++m) {
#pragma unroll
    for (int r = 0; r < 4; ++r) {
      const int i = bi * 256 + wm * 128 + m * 16 + fq * 4 + r;
      const int li = label[i];
      const float sqi = sq[i];
      float bestv = -3.0e38f;
      int bestj = 0x7FFFFFFF;
#pragma unroll
      for (int n = 0; n < 4; ++n) {
        const int j = bj * 256 + wn * 64 + n * 16 + fr;
        const float val = sqi + sq[j] - 2.0f * acc[m][n][r] + cst;
        if (label[j] != li && val > bestv) { bestv = val; bestj = j; }
      }
      unsigned long long pack =
          (bestj == 0x7FFFFFFF)
              ? 0ull
              : (((unsigned long long)fenc(bestv)) << 32) | (unsigned)(~bestj);
#pragma unroll
      for (int off = 1; off < 16; off <<= 1) {
        unsigned long long o = __shfl_xor(pack, off, 64);
        if (o > pack) pack = o;
      }
      if (fr == 0 && pack) atomicMax(&hard[i], pack);
    }
  }
}

// ---------------- K4: InfoNCE per-row term (3 f32 dots + log_softmax) --------
__global__ __launch_bounds__(256) void k_nce(
    const float* __restrict__ outs, const float* __restrict__ centers,
    const int* __restrict__ label, const unsigned long long* __restrict__ hard,
    const int* __restrict__ ridx, float* __restrict__ nce) {
  const int i = blockIdx.x;
  const int tid = threadIdx.x;
  const int lane = tid & 63, wid = tid >> 6;
  const int li = label[i];
  const int jh = (int)(~(uint32_t)hard[i]);
  const int jr = ridx[i];
  const float4 a  = reinterpret_cast<const float4*>(outs + (size_t)i * Csz)[tid];
  const float4 c  = reinterpret_cast<const float4*>(centers + (size_t)li * Csz)[tid];
  const float4 rr = reinterpret_cast<const float4*>(outs + (size_t)jr * Csz)[tid];
  const float4 hh = reinterpret_cast<const float4*>(outs + (size_t)jh * Csz)[tid];
  float dp = a.x * c.x + a.y * c.y + a.z * c.z + a.w * c.w;
  float dr = a.x * rr.x + a.y * rr.y + a.z * rr.z + a.w * rr.w;
  float dh = a.x * hh.x + a.y * hh.y + a.z * hh.z + a.w * hh.w;
#pragma unroll
  for (int off = 32; off; off >>= 1) {
    dp += __shfl_xor(dp, off, 64);
    dr += __shfl_xor(dr, off, 64);
    dh += __shfl_xor(dh, off, 64);
  }
  __shared__ float w0[4], w1[4], w2[4];
  if (lane == 0) { w0[wid] = dp; w1[wid] = dr; w2[wid] = dh; }
  __syncthreads();
  if (tid == 0) {
    const float l0 = w0[0] + w0[1] + w0[2] + w0[3];
    const float l1 = w1[0] + w1[1] + w1[2] + w1[3];
    const float l2 = w2[0] + w2[1] + w2[2] + w2[3];
    const float m = fmaxf(l0, fmaxf(l1, l2));
    const float lse = logf(expf(l0 - m) + expf(l1 - m) + expf(l2 - m));
    nce[i] = -(l0 - m - lse);
  }
}

// ---------------- K5: deterministic final reduction --------------------------
__global__ __launch_bounds__(1024) void k_final(
    const float* __restrict__ ce, const float* __restrict__ nce,
    float* __restrict__ out) {
  __shared__ double s[1024];
  const int tid = threadIdx.x;
  double v = 0.0;
#pragma unroll
  for (int q = 0; q < 4; ++q) {
    v += (double)ce[tid + q * 1024];
    v += 0.1 * (double)nce[tid + q * 1024];
  }
  s[tid] = v;
  __syncthreads();
  for (int off = 512; off; off >>= 1) {
    if (tid < off) s[tid] += s[tid + off];
    __syncthreads();
  }
  if (tid == 0) out[0] = (float)(s[0] / 4096.0);
}

extern "C" void kernel_launch(void* const* d_in, const int* in_sizes, int n_in,
                              void* d_out, int out_size, void* d_ws, size_t ws_size,
                              hipStream_t stream) {
  const float* outs = (const float*)d_in[0];
  const float* centers = (const float*)d_in[1];
  const int* label = (const int*)d_in[2];
  float* out = (float*)d_out;

  char* ws = (char*)d_ws;
  unsigned short* xb = (unsigned short*)ws;                            // 8 MB bf16 X
  unsigned long long* hard = (unsigned long long*)(ws + (8u << 20));   // 32 KB
  float* sq = (float*)(ws + (8u << 20) + 32768);                       // 16 KB
  float* ce = sq + Bsz;                                                // 16 KB
  float* nce = ce + Bsz;                                               // 16 KB
  int* ridx = (int*)(nce + Bsz);                                       // 16 KB

  k_rowstats<<<Bsz, 256, 0, stream>>>(outs, label, xb, sq, ce, hard, ridx);
  k_hard<<<256, 512, 0, stream>>>(xb, sq, label, hard);
  k_nce<<<Bsz, 256, 0, stream>>>(outs, centers, label, hard, ridx, nce);
  k_final<<<1, 1024, 0, stream>>>(ce, nce, out);
}

// Round 10
// 158.147 us; speedup vs baseline: 1.7366x; 1.0117x over previous
//
#include <hip/hip_runtime.h>
#include <hip/hip_bf16.h>
#include <stdint.h>

#define Bsz 4096
#define Csz 1024

typedef __attribute__((ext_vector_type(8))) short short8;
typedef __attribute__((ext_vector_type(4))) float f32x4;

// order-preserving f32 -> u32 encoding (monotone for all non-NaN)
__device__ __forceinline__ unsigned fenc(float v) {
  unsigned u = __float_as_uint(v);
  return (u & 0x80000000u) ? ~u : (u | 0x80000000u);
}

__device__ __forceinline__ void load_lds16(const void* g, void* l) {
  __builtin_amdgcn_global_load_lds(
      (const __attribute__((address_space(1))) void*)g,
      (__attribute__((address_space(3))) void*)l, 16, 0, 0);
}

__device__ __forceinline__ uint32_t rotl32(uint32_t x, int r) {
  return (x << r) | (x >> (32 - r));
}

// ---------------- K1: row stats + bf16 cast + fused threefry rand_idx -------
__global__ __launch_bounds__(256) void k_rowstats(
    const float* __restrict__ outs, const int* __restrict__ label,
    unsigned short* __restrict__ xb, float* __restrict__ sq,
    float* __restrict__ ce, unsigned long long* __restrict__ hard,
    int* __restrict__ ridx) {
  const int row = blockIdx.x;
  const int tid = threadIdx.x;
  const int lane = tid & 63, wid = tid >> 6;
  const float4 v = reinterpret_cast<const float4*>(outs + (size_t)row * Csz)[tid];

  ushort4 u4;
  {
    __hip_bfloat16 h;
    h = __float2bfloat16(v.x); u4.x = *reinterpret_cast<const unsigned short*>(&h);
    h = __float2bfloat16(v.y); u4.y = *reinterpret_cast<const unsigned short*>(&h);
    h = __float2bfloat16(v.z); u4.z = *reinterpret_cast<const unsigned short*>(&h);
    h = __float2bfloat16(v.w); u4.w = *reinterpret_cast<const unsigned short*>(&h);
  }
  reinterpret_cast<ushort4*>(xb + (size_t)row * Csz)[tid] = u4;

  __shared__ float wred[3][4];
  float mx = fmaxf(fmaxf(v.x, v.y), fmaxf(v.z, v.w));
#pragma unroll
  for (int off = 32; off; off >>= 1) mx = fmaxf(mx, __shfl_xor(mx, off, 64));
  if (lane == 0) wred[0][wid] = mx;
  __syncthreads();
  mx = fmaxf(fmaxf(wred[0][0], wred[0][1]), fmaxf(wred[0][2], wred[0][3]));

  float se = expf(v.x - mx) + expf(v.y - mx) + expf(v.z - mx) + expf(v.w - mx);
  float s2 = v.x * v.x + v.y * v.y + v.z * v.z + v.w * v.w;
#pragma unroll
  for (int off = 32; off; off >>= 1) {
    se += __shfl_xor(se, off, 64);
    s2 += __shfl_xor(s2, off, 64);
  }
  if (lane == 0) { wred[1][wid] = se; wred[2][wid] = s2; }
  __syncthreads();
  if (tid == 0) {
    const float set = wred[1][0] + wred[1][1] + wred[1][2] + wred[1][3];
    const float sqt = wred[2][0] + wred[2][1] + wred[2][2] + wred[2][3];
    sq[row] = sqt;
    ce[row] = -(outs[(size_t)row * Csz + label[row]] - mx - logf(set));
    hard[row] = 0ull;  // fused memset
  }

  if (row >= 2048) return;

  // ---- fused rand_idx: rows row and row+2048 ----
  const int i = row;
  const int li0 = label[i], li1 = label[i + 2048];
  const uint32_t k1c = 42u, k2c = 0x1BD11BDAu ^ 42u;
  unsigned long long b0 = 0ull, b1 = 0ull;
  for (int j = tid; j < Bsz; j += 256) {
    uint32_t x0 = (uint32_t)(i * Bsz + j);
    uint32_t x1 = x0 + 8388608u;
    x1 += k1c;
#define RND(rt) { x0 += x1; x1 = rotl32(x1, rt); x1 ^= x0; }
    RND(13) RND(15) RND(26) RND(6)
    x0 += k1c; x1 += k2c + 1u;
    RND(17) RND(29) RND(16) RND(24)
    x0 += k2c; x1 += 2u;
    RND(13) RND(15) RND(26) RND(6)
    x1 += k1c + 3u;
    RND(17) RND(29) RND(16) RND(24)
    x0 += k1c; x1 += k2c + 4u;
    RND(13) RND(15) RND(26) RND(6)
    x0 += k2c; x1 += 5u;
#undef RND
    const int lj = label[j];
    if (lj != li0) {
      unsigned long long p = (((unsigned long long)(x0 >> 9)) << 32) | (uint32_t)(~j);
      if (p > b0) b0 = p;
    }
    if (lj != li1) {
      unsigned long long p = (((unsigned long long)(x1 >> 9)) << 32) | (uint32_t)(~j);
      if (p > b1) b1 = p;
    }
  }
#pragma unroll
  for (int off = 32; off; off >>= 1) {
    unsigned long long o0 = __shfl_xor(b0, off, 64); if (o0 > b0) b0 = o0;
    unsigned long long o1 = __shfl_xor(b1, off, 64); if (o1 > b1) b1 = o1;
  }
  __shared__ unsigned long long r0[4], r1[4];
  if (lane == 0) { r0[wid] = b0; r1[wid] = b1; }
  __syncthreads();
  if (tid == 0) {
#pragma unroll
    for (int w = 1; w < 4; ++w) {
      if (r0[w] > b0) b0 = r0[w];
      if (r1[w] > b1) b1 = r1[w];
    }
    ridx[i] = (int)(~(uint32_t)b0);
    ridx[i + 2048] = (int)(~(uint32_t)b1);
  }
}

// ---------------- K2: bf16 MFMA X·X^T, 256x256, m201-style 8-phase ----------
// 256 blocks (1/CU), 8 waves 2Mx4N, per-wave 128x64 = 8x4 frags of 16x16.
// BK=64 (128B LDS rows, full 8-slot swizzle, r7-proven 0-conflict), 16
// K-tiles, buf = tile&1. 8 phases per iteration (2 K-tiles); each phase:
// {8 ds_read_b128 (one (kh,mh) quadrant) + 2 global_load_lds (one 128-row
// chunk whose last reader was the PREVIOUS phase) -> barrier -> lgkmcnt(0)
// -> setprio(1) 16 MFMA setprio(0) -> barrier}. Stage plan per iter j:
// P1-P3: tile 2j+1's A-mh1,B-p1,B-p2 (buf1; its A-mh0 staged at prev P8);
// P4-P7: tile 2j+2 (buf0); P8: tile 2j+3's A-mh0 (buf1). vmcnt(2) only at
// P1/P5 (2 newest loads = other buffer's), vmcnt(0) only at j=7's P5.
// Region-freeing: A-mh free after its kh1 phase (P3/P4, P7/P8); B free
// after P4/P8 -- every stage targets a just-freed region (issued after the
// freeing phase's closing barrier). Rule-18 sched_barrier after waitcnts.
__global__ __launch_bounds__(512, 2) void k_hard(
    const unsigned short* __restrict__ xb, const float* __restrict__ sq,
    const int* __restrict__ label, unsigned long long* __restrict__ hard) {
  __shared__ unsigned short As[2][256 * 64];
  __shared__ unsigned short Bs[2][256 * 64];

  const int bid = (int)blockIdx.x;
  const int swz = (bid & 7) * 32 + (bid >> 3);  // XCD swizzle (256 = 8*32)
  const int bi = swz >> 4, bj = swz & 15;

  const int tid = (int)threadIdx.x;
  const int wid = tid >> 6, lane = tid & 63;
  const int wm = wid >> 2;    // 0..1: wave row (128 rows)
  const int wn = wid & 3;     // 0..3: wave col (64 cols)
  const int fr = lane & 15;   // fragment row/col index
  const int fq = lane >> 4;   // k-quad index

  f32x4 acc[8][4];
#pragma unroll
  for (int m = 0; m < 8; ++m)
#pragma unroll
    for (int n = 0; n < 4; ++n) acc[m][n] = (f32x4){0.f, 0.f, 0.f, 0.f};

  const unsigned short* Ag = xb + (size_t)(bi * 256) * Csz;
  const unsigned short* Bg = xb + (size_t)(bj * 256) * Csz;
  const int lrow = lane >> 3;                 // row within 8-row staging inst
  const int lch = ((lane & 7) ^ lrow) * 8;    // pre-swizzled source chunk

// stage A rows {mh*64..+63} and {128+mh*64..+63} (the two wave-halves' mh
// slices) of K-tile at col kt into As[b]; 2 insts/wave, 8 rows each
#define STAGE_A_MH(b, kt, mh) { \
    const int rb0 = (mh) * 64 + wid * 8; \
    load_lds16(Ag + (size_t)(rb0 + lrow) * Csz + (kt) + lch, &As[b][rb0 * 64]); \
    const int rb1 = 128 + (mh) * 64 + wid * 8; \
    load_lds16(Ag + (size_t)(rb1 + lrow) * Csz + (kt) + lch, &As[b][rb1 * 64]); }
// stage B rows {p*128..+127}
#define STAGE_B_P(b, kt, p) { \
    const int rb0 = (p) * 128 + wid * 8; \
    load_lds16(Bg + (size_t)(rb0 + lrow) * Csz + (kt) + lch, &Bs[b][rb0 * 64]); \
    const int rb1 = (p) * 128 + 64 + wid * 8; \
    load_lds16(Bg + (size_t)(rb1 + lrow) * Csz + (kt) + lch, &Bs[b][rb1 * 64]); }

#define VMSYNC(NSTR) { \
    asm volatile("s_waitcnt vmcnt(" NSTR ")" ::: "memory"); \
    __builtin_amdgcn_sched_barrier(0); \
    __builtin_amdgcn_s_barrier(); }

#define PHASE(bbuf, kh, mh, STAGE_STMT) { \
    short8 af[4], bf[4]; \
    const int co = (((kh) * 4 + fq) ^ (fr & 7)) * 8; \
    _Pragma("unroll") \
    for (int m = 0; m < 4; ++m) \
      af[m] = *reinterpret_cast<const short8*>( \
          &As[bbuf][(wm * 128 + (mh) * 64 + m * 16 + fr) * 64 + co]); \
    _Pragma("unroll") \
    for (int n = 0; n < 4; ++n) \
      bf[n] = *reinterpret_cast<const short8*>( \
          &Bs[bbuf][(wn * 64 + n * 16 + fr) * 64 + co]); \
    STAGE_STMT; \
    __builtin_amdgcn_s_barrier(); \
    asm volatile("s_waitcnt lgkmcnt(0)" ::: "memory"); \
    __builtin_amdgcn_sched_barrier(0); \
    __builtin_amdgcn_s_setprio(1); \
    _Pragma("unroll") \
    for (int m = 0; m < 4; ++m) \
      _Pragma("unroll") \
      for (int n = 0; n < 4; ++n) \
        acc[(mh) * 4 + m][n] = __builtin_amdgcn_mfma_f32_16x16x32_bf16( \
            af[m], bf[n], acc[(mh) * 4 + m][n], 0, 0, 0); \
    __builtin_amdgcn_s_setprio(0); \
    __builtin_amdgcn_s_barrier(); }

  // prologue: tile 0 fully (8 insts) + tile 1's A-mh0 (2 insts)
  STAGE_A_MH(0, 0, 0); STAGE_A_MH(0, 0, 1);
  STAGE_B_P(0, 0, 0);  STAGE_B_P(0, 0, 1);
  STAGE_A_MH(1, 64, 0);

#pragma unroll 1
  for (int j = 0; j < 8; ++j) {
    const int ktB = j * 128 + 64;   // tile 2j+1 (buf1, read P5-P8)
    const int ktC = j * 128 + 128;  // tile 2j+2 (buf0, next iter)
    const int ktD = j * 128 + 192;  // tile 2j+3 (buf1, next iter)
    VMSYNC("2");                                        // buf0 stages landed
    PHASE(0, 0, 0, STAGE_A_MH(1, ktB, 1));              // P1
    PHASE(0, 0, 1, STAGE_B_P(1, ktB, 0));               // P2
    PHASE(0, 1, 0, STAGE_B_P(1, ktB, 1));               // P3
    PHASE(0, 1, 1, if (j < 7) STAGE_A_MH(0, ktC, 0));   // P4
    if (j < 7) { VMSYNC("2"); } else { VMSYNC("0"); }   // buf1 stages landed
    PHASE(1, 0, 0, if (j < 7) STAGE_A_MH(0, ktC, 1));   // P5
    PHASE(1, 0, 1, if (j < 7) STAGE_B_P(0, ktC, 0));    // P6
    PHASE(1, 1, 0, if (j < 7) STAGE_B_P(0, ktC, 1));    // P7
    PHASE(1, 1, 1, if (j < 7) STAGE_A_MH(1, ktD, 0));   // P8
  }
#undef PHASE
#undef VMSYNC
#undef STAGE_A_MH
#undef STAGE_B_P

  const float cst = -2.0f * 1024.0f * 3.1622776601683794e-8f;  // -2*c*sqrt(1e-15)

  // epilogue: C/D layout col(B-side)=lane&15, row(A-side)=fq*4+reg
#pragma unroll
  for (int m = 0; m < 8; ++m) {
#pragma unroll
    for (int r = 0; r < 4; ++r) {
      const int i = bi * 256 + wm * 128 + m * 16 + fq * 4 + r;
      const int li = label[i];
      const float sqi = sq[i];
      float bestv = -3.0e38f;
      int bestj = 0x7FFFFFFF;
#pragma unroll
      for (int n = 0; n < 4; ++n) {
        const int j = bj * 256 + wn * 64 + n * 16 + fr;
        const float val = sqi + sq[j] - 2.0f * acc[m][n][r] + cst;
        if (label[j] != li && val > bestv) { bestv = val; bestj = j; }
      }
      unsigned long long pack =
          (bestj == 0x7FFFFFFF)
              ? 0ull
              : (((unsigned long long)fenc(bestv)) << 32) | (unsigned)(~bestj);
#pragma unroll
      for (int off = 1; off < 16; off <<= 1) {
        unsigned long long o = __shfl_xor(pack, off, 64);
        if (o > pack) pack = o;
      }
      if (fr == 0 && pack) atomicMax(&hard[i], pack);
    }
  }
}

// ---------------- K4: InfoNCE per-row term (3 f32 dots + log_softmax) --------
__global__ __launch_bounds__(256) void k_nce(
    const float* __restrict__ outs, const float* __restrict__ centers,
    const int* __restrict__ label, const unsigned long long* __restrict__ hard,
    const int* __restrict__ ridx, float* __restrict__ nce) {
  const int i = blockIdx.x;
  const int tid = threadIdx.x;
  const int lane = tid & 63, wid = tid >> 6;
  const int li = label[i];
  const int jh = (int)(~(uint32_t)hard[i]);
  const int jr = ridx[i];
  const float4 a  = reinterpret_cast<const float4*>(outs + (size_t)i * Csz)[tid];
  const float4 c  = reinterpret_cast<const float4*>(centers + (size_t)li * Csz)[tid];
  const float4 rr = reinterpret_cast<const float4*>(outs + (size_t)jr * Csz)[tid];
  const float4 hh = reinterpret_cast<const float4*>(outs + (size_t)jh * Csz)[tid];
  float dp = a.x * c.x + a.y * c.y + a.z * c.z + a.w * c.w;
  float dr = a.x * rr.x + a.y * rr.y + a.z * rr.z + a.w * rr.w;
  float dh = a.x * hh.x + a.y * hh.y + a.z * hh.z + a.w * hh.w;
#pragma unroll
  for (int off = 32; off; off >>= 1) {
    dp += __shfl_xor(dp, off, 64);
    dr += __shfl_xor(dr, off, 64);
    dh += __shfl_xor(dh, off, 64);
  }
  __shared__ float w0[4], w1[4], w2[4];
  if (lane == 0) { w0[wid] = dp; w1[wid] = dr; w2[wid] = dh; }
  __syncthreads();
  if (tid == 0) {
    const float l0 = w0[0] + w0[1] + w0[2] + w0[3];
    const float l1 = w1[0] + w1[1] + w1[2] + w1[3];
    const float l2 = w2[0] + w2[1] + w2[2] + w2[3];
    const float m = fmaxf(l0, fmaxf(l1, l2));
    const float lse = logf(expf(l0 - m) + expf(l1 - m) + expf(l2 - m));
    nce[i] = -(l0 - m - lse);
  }
}

// ---------------- K5: deterministic final reduction --------------------------
__global__ __launch_bounds__(1024) void k_final(
    const float* __restrict__ ce, const float* __restrict__ nce,
    float* __restrict__ out) {
  __shared__ double s[1024];
  const int tid = threadIdx.x;
  double v = 0.0;
#pragma unroll
  for (int q = 0; q < 4; ++q) {
    v += (double)ce[tid + q * 1024];
    v += 0.1 * (double)nce[tid + q * 1024];
  }
  s[tid] = v;
  __syncthreads();
  for (int off = 512; off; off >>= 1) {
    if (tid < off) s[tid] += s[tid + off];
    __syncthreads();
  }
  if (tid == 0) out[0] = (float)(s[0] / 4096.0);
}

extern "C" void kernel_launch(void* const* d_in, const int* in_sizes, int n_in,
                              void* d_out, int out_size, void* d_ws, size_t ws_size,
                              hipStream_t stream) {
  const float* outs = (const float*)d_in[0];
  const float* centers = (const float*)d_in[1];
  const int* label = (const int*)d_in[2];
  float* out = (float*)d_out;

  char* ws = (char*)d_ws;
  unsigned short* xb = (unsigned short*)ws;                            // 8 MB bf16 X
  unsigned long long* hard = (unsigned long long*)(ws + (8u << 20));   // 32 KB
  float* sq = (float*)(ws + (8u << 20) + 32768);                       // 16 KB
  float* ce = sq + Bsz;                                                // 16 KB
  float* nce = ce + Bsz;                                               // 16 KB
  int* ridx = (int*)(nce + Bsz);                                       // 16 KB

  k_rowstats<<<Bsz, 256, 0, stream>>>(outs, label, xb, sq, ce, hard, ridx);
  k_hard<<<256, 512, 0, stream>>>(xb, sq, label, hard);
  k_nce<<<Bsz, 256, 0, stream>>>(outs, centers, label, hard, ridx, nce);
  k_final<<<1, 1024, 0, stream>>>(ce, nce, out);
}